// Round 2
// baseline (531.597 us; speedup 1.0000x reference)
//
#include <hip/hip_runtime.h>

// ---------------------------------------------------------------------------
// Fused causal attention, MI355X gfx950.
// cast fp32->f16 -> QKV GEMM (global_load_lds staging) -> V transpose ->
// flash attention (barrier-free hot loop, direct-global K/V frags) ->
// output GEMM (fp32 out).
// MFMA 16x16x32 layouts (m89/m91/m120-verified):
//   A-frag: A[m=lane&15][k=(lane>>4)*8+j], j=0..7
//   B-frag: B[k=(lane>>4)*8+j][n=lane&15]
//   C/D   : row=(lane>>4)*4+reg, col=lane&15
// ---------------------------------------------------------------------------

typedef _Float16 f16x8 __attribute__((ext_vector_type(8)));
typedef float floatx4 __attribute__((ext_vector_type(4)));

union U4H8 { uint4 u; f16x8 h; };

__device__ __forceinline__ ushort f32_to_h_bits(float f) {
  _Float16 h = (_Float16)f;
  return __builtin_bit_cast(ushort, h);
}

// async global->LDS, 16B per lane; lds dest = wave-uniform base + lane*16
__device__ __forceinline__ void gld16(const void* g, void* l) {
  __builtin_amdgcn_global_load_lds(
      (const __attribute__((address_space(1))) unsigned char*)g,
      (__attribute__((address_space(3))) unsigned char*)l, 16, 0, 0);
}

// ---------------------------------------------------------------- cast kernel
__global__ __launch_bounds__(256) void cast_f32_f16(const float* __restrict__ in,
                                                    ushort* __restrict__ out) {
  int i = blockIdx.x * 256 + threadIdx.x;
  float4 v = ((const float4*)in)[i];
  ushort4 o;
  o.x = f32_to_h_bits(v.x);
  o.y = f32_to_h_bits(v.y);
  o.z = f32_to_h_bits(v.z);
  o.w = f32_to_h_bits(v.w);
  ((ushort4*)out)[i] = o;
}

// ------------------------------------------------------------------ GEMM B^T
// C[M,N] = A[M,K] * B[N,K]^T.  128x128 tile, BK=32, 4 waves 2x2, 4x4 MFMA each.
// Staging via global_load_lds width=16 (m97 pattern): LDS layout is lane-linear.
template <int OUT_F16>
__global__ __launch_bounds__(256) void gemm_bt(const ushort* __restrict__ A,
                                               const ushort* __restrict__ B,
                                               void* __restrict__ Cv,
                                               int M, int N, int K) {
  __shared__ ushort As[128 * 32];
  __shared__ ushort Bs[128 * 32];

  const int tid = threadIdx.x;
  const int lane = tid & 63;
  const int wid = tid >> 6;
  const int l15 = lane & 15;
  const int quad = lane >> 4;
  const int m0 = blockIdx.y * 128;
  const int n0 = blockIdx.x * 128;
  const int wm = (wid & 1) * 64;
  const int wn = (wid >> 1) * 64;

  floatx4 acc[4][4];
#pragma unroll
  for (int i = 0; i < 4; i++)
#pragma unroll
    for (int j = 0; j < 4; j++) acc[i][j] = (floatx4){0.f, 0.f, 0.f, 0.f};

  const int srow = tid >> 2;
  const int scol = (tid & 3) * 8;
  const ushort* Ap0 = A + (size_t)(m0 + srow) * K + scol;
  const ushort* Ap1 = A + (size_t)(m0 + 64 + srow) * K + scol;
  const ushort* Bp0 = B + (size_t)(n0 + srow) * K + scol;
  const ushort* Bp1 = B + (size_t)(n0 + 64 + srow) * K + scol;
  // per-wave LDS staging bases: lane L lands at base + L*16B == ushort tid*8
  ushort* AsW = As + wid * 512;
  ushort* BsW = Bs + wid * 512;

  for (int k0 = 0; k0 < K; k0 += 32) {
    __syncthreads();  // previous iteration's frag reads done before overwrite
    gld16(Ap0 + k0, AsW);
    gld16(Ap1 + k0, AsW + 2048);
    gld16(Bp0 + k0, BsW);
    gld16(Bp1 + k0, BsW + 2048);
    __syncthreads();  // drains vmcnt(0): staged data visible

    U4H8 af[4], bf[4];
#pragma unroll
    for (int mi = 0; mi < 4; mi++)
      af[mi].u = *(const uint4*)&As[(wm + mi * 16 + l15) * 32 + quad * 8];
#pragma unroll
    for (int ni = 0; ni < 4; ni++)
      bf[ni].u = *(const uint4*)&Bs[(wn + ni * 16 + l15) * 32 + quad * 8];
#pragma unroll
    for (int mi = 0; mi < 4; mi++)
#pragma unroll
      for (int ni = 0; ni < 4; ni++)
        acc[mi][ni] = __builtin_amdgcn_mfma_f32_16x16x32_f16(af[mi].h, bf[ni].h,
                                                             acc[mi][ni], 0, 0, 0);
  }

#pragma unroll
  for (int mi = 0; mi < 4; mi++) {
#pragma unroll
    for (int r = 0; r < 4; r++) {
      size_t row = m0 + wm + mi * 16 + quad * 4 + r;
#pragma unroll
      for (int ni = 0; ni < 4; ni++) {
        size_t col = n0 + wn + ni * 16 + l15;
        float v = acc[mi][ni][r];
        if (OUT_F16)
          ((ushort*)Cv)[row * N + col] = f32_to_h_bits(v);
        else
          ((float*)Cv)[row * N + col] = v;
      }
    }
  }
}

// --------------------------------------------------------------- V transpose
// qkv [8192][3072] f16 -> vtg[bh=64][dh=64][key=2048] f16.
// Block = (64-key tile, bh). Tiny kernel (~33 MB traffic).
__global__ __launch_bounds__(256) void vtrans(const ushort* __restrict__ qkv,
                                              ushort* __restrict__ vtg) {
  __shared__ ushort T[64 * 66];  // [dh][key], stride 66 (round-1 proven pattern)
  const int tid = threadIdx.x;
  const int kt = blockIdx.x;
  const int bh = blockIdx.y;
  const int b = bh >> 4, h = bh & 15;

  const int r = tid >> 3;          // 0..31 (and +32): local key row
  const int c = (tid & 7) * 8;     // dh chunk
  const ushort* src = qkv + (size_t)(b * 2048 + kt * 64) * 3072 + 2048 + h * 64;
  uint4 v0 = *(const uint4*)(src + (size_t)r * 3072 + c);
  uint4 v1 = *(const uint4*)(src + (size_t)(r + 32) * 3072 + c);
  union { uint4 u; ushort s[8]; } a0, a1;
  a0.u = v0; a1.u = v1;
#pragma unroll
  for (int j = 0; j < 8; j++) {
    T[(c + j) * 66 + r] = a0.s[j];
    T[(c + j) * 66 + r + 32] = a1.s[j];
  }
  __syncthreads();

  const int d = tid >> 3;          // dh row (0..31, +32)
  const int kc = (tid & 7) * 8;    // key chunk
  ushort* dst = vtg + (size_t)bh * 64 * 2048 + (size_t)kt * 64;
  union { uint u[4]; uint4 u4; } o0, o1;
#pragma unroll
  for (int i = 0; i < 4; i++) {
    o0.u[i] = *(const uint*)&T[d * 66 + kc + 2 * i];
    o1.u[i] = *(const uint*)&T[(d + 32) * 66 + kc + 2 * i];
  }
  *(uint4*)(dst + (size_t)d * 2048 + kc) = o0.u4;
  *(uint4*)(dst + (size_t)(d + 32) * 2048 + kc) = o1.u4;
}

// ------------------------------------------------------------ flash attention
// Barrier-free hot loop: K/V frags direct from global (L1/L2-resident tiles),
// only LDS use is the per-wave P round-trip synced by lgkmcnt(0).
// Block = 128 q-rows x (b,h); 4 independent waves x 32 q-rows.
__global__ __launch_bounds__(256) void attn_fused(const ushort* __restrict__ qkv,
                                                  const ushort* __restrict__ vtg,
                                                  ushort* __restrict__ attn_out) {
  __shared__ ushort Ps[4][32 * 72];

  const int tid = threadIdx.x;
  const int lane = tid & 63;
  const int w = tid >> 6;
  const int l15 = lane & 15;
  const int quad = lane >> 4;
  const int qt = (int)gridDim.x - 1 - (int)blockIdx.x;  // big tiles first
  const int bh = blockIdx.y;
  const int b = bh >> 4;
  const int h = bh & 15;
  const int bS = b * 2048;
  const int qw0 = qt * 128 + w * 32;   // this wave's first q row

  // Q A-frags for both 16-row sets, pre-scaled by 1/sqrt(64)
  U4H8 qf[2][2];
#pragma unroll
  for (int qs = 0; qs < 2; qs++) {
    const ushort* qrow = qkv + (size_t)(bS + qw0 + qs * 16 + l15) * 3072 + h * 64;
    qf[qs][0].u = *(const uint4*)(qrow + quad * 8);
    qf[qs][1].u = *(const uint4*)(qrow + 32 + quad * 8);
    qf[qs][0].h = qf[qs][0].h * (_Float16)0.125f;
    qf[qs][1].h = qf[qs][1].h * (_Float16)0.125f;
  }

  floatx4 o[2][4];
#pragma unroll
  for (int qs = 0; qs < 2; qs++)
#pragma unroll
    for (int ni = 0; ni < 4; ni++) o[qs][ni] = (floatx4){0.f, 0.f, 0.f, 0.f};
  float m_i[2][4], l_i[2][4];
#pragma unroll
  for (int qs = 0; qs < 2; qs++)
#pragma unroll
    for (int r = 0; r < 4; r++) { m_i[qs][r] = -1e30f; l_i[qs][r] = 0.f; }

  const ushort* kbase = qkv + (size_t)bS * 3072 + 1024 + h * 64;
  const ushort* vbase = vtg + (size_t)bh * 64 * 2048;

  const int ntiles = (qw0 + 95) >> 6;  // exactly one (the last) is diagonal

  for (int kt = 0; kt < ntiles; ++kt) {
    const bool diag = (kt == ntiles - 1);
    const int n16 = diag ? (((qw0 + 31 - (kt << 6)) >> 4) + 1) : 4;

    // V B-frags for this tile (issued early; contiguous b128 from vtg)
    U4H8 vf[4][2];
#pragma unroll
    for (int ni = 0; ni < 4; ni++)
#pragma unroll
      for (int kc = 0; kc < 2; kc++)
        vf[ni][kc].u = *(const uint4*)(vbase + (size_t)(ni * 16 + l15) * 2048 +
                                       kt * 64 + kc * 32 + quad * 8);

    // ---- S = Q K^T (K frags direct from global, contiguous b128)
    floatx4 s4[2][4];
    for (int t16 = 0; t16 < n16; t16++) {
      U4H8 kf0, kf1;
      const ushort* krow = kbase + (size_t)(kt * 64 + t16 * 16 + l15) * 3072;
      kf0.u = *(const uint4*)(krow + quad * 8);
      kf1.u = *(const uint4*)(krow + 32 + quad * 8);
#pragma unroll
      for (int qs = 0; qs < 2; qs++) {
        floatx4 sa = (floatx4){0.f, 0.f, 0.f, 0.f};
        sa = __builtin_amdgcn_mfma_f32_16x16x32_f16(qf[qs][0].h, kf0.h, sa, 0, 0, 0);
        sa = __builtin_amdgcn_mfma_f32_16x16x32_f16(qf[qs][1].h, kf1.h, sa, 0, 0, 0);
        s4[qs][t16] = sa;
      }
    }
    if (n16 < 4) {
#pragma unroll
      for (int qs = 0; qs < 2; qs++)
        for (int t16 = n16; t16 < 4; t16++)
          s4[qs][t16] = (floatx4){-1e30f, -1e30f, -1e30f, -1e30f};
    }
    if (diag) {  // mask only on the single diagonal tile
#pragma unroll
      for (int qs = 0; qs < 2; qs++)
        for (int t16 = 0; t16 < n16; t16++) {
          const int key = (kt << 6) + t16 * 16 + l15;
#pragma unroll
          for (int r = 0; r < 4; r++) {
            int q = qw0 + qs * 16 + quad * 4 + r;
            if (key > q) s4[qs][t16][r] = -1e30f;
          }
        }
    }

    // ---- online softmax + P write (per 16-row set)
#pragma unroll
    for (int qs = 0; qs < 2; qs++) {
      float alpha[4];
#pragma unroll
      for (int r = 0; r < 4; r++) {
        float tmax = fmaxf(fmaxf(s4[qs][0][r], s4[qs][1][r]),
                           fmaxf(s4[qs][2][r], s4[qs][3][r]));
        tmax = fmaxf(tmax, __shfl_xor(tmax, 1));
        tmax = fmaxf(tmax, __shfl_xor(tmax, 2));
        tmax = fmaxf(tmax, __shfl_xor(tmax, 4));
        tmax = fmaxf(tmax, __shfl_xor(tmax, 8));
        float mnew = fmaxf(m_i[qs][r], tmax);
        alpha[r] = __expf(m_i[qs][r] - mnew);
        m_i[qs][r] = mnew;
        float rs = 0.f;
#pragma unroll
        for (int t16 = 0; t16 < 4; t16++) {
          float p = __expf(s4[qs][t16][r] - mnew);
          s4[qs][t16][r] = p;
          rs += p;
        }
        rs += __shfl_xor(rs, 1);
        rs += __shfl_xor(rs, 2);
        rs += __shfl_xor(rs, 4);
        rs += __shfl_xor(rs, 8);
        l_i[qs][r] = l_i[qs][r] * alpha[r] + rs;
      }
#pragma unroll
      for (int ni = 0; ni < 4; ni++)
#pragma unroll
        for (int r = 0; r < 4; r++) o[qs][ni][r] *= alpha[r];
#pragma unroll
      for (int t16 = 0; t16 < 4; t16++)
#pragma unroll
        for (int r = 0; r < 4; r++)
          Ps[w][(qs * 16 + quad * 4 + r) * 72 + t16 * 16 + l15] =
              f32_to_h_bits(s4[qs][t16][r]);
    }

    // within-wave LDS RAW: DS pipe is in-order per wave; drain lgkm, no barrier
    __asm__ volatile("s_waitcnt lgkmcnt(0)" ::: "memory");

    // ---- O += P V
#pragma unroll
    for (int qs = 0; qs < 2; qs++) {
      U4H8 pa0, pa1;
      pa0.u = *(const uint4*)&Ps[w][(qs * 16 + l15) * 72 + quad * 8];
      pa1.u = *(const uint4*)&Ps[w][(qs * 16 + l15) * 72 + 32 + quad * 8];
#pragma unroll
      for (int ni = 0; ni < 4; ni++) {
        o[qs][ni] = __builtin_amdgcn_mfma_f32_16x16x32_f16(pa0.h, vf[ni][0].h,
                                                           o[qs][ni], 0, 0, 0);
        o[qs][ni] = __builtin_amdgcn_mfma_f32_16x16x32_f16(pa1.h, vf[ni][1].h,
                                                           o[qs][ni], 0, 0, 0);
      }
    }
  }

  // ---- epilogue
#pragma unroll
  for (int qs = 0; qs < 2; qs++)
#pragma unroll
    for (int r = 0; r < 4; r++) {
      float inv = 1.0f / l_i[qs][r];
      int q = qw0 + qs * 16 + quad * 4 + r;
      ushort* orow = attn_out + (size_t)(bS + q) * 1024 + h * 64;
#pragma unroll
      for (int ni = 0; ni < 4; ni++)
        orow[ni * 16 + l15] = f32_to_h_bits(o[qs][ni][r] * inv);
    }
}

// ---------------------------------------------------------------------- launch
extern "C" void kernel_launch(void* const* d_in, const int* in_sizes, int n_in,
                              void* d_out, int out_size, void* d_ws, size_t ws_size,
                              hipStream_t stream) {
  const float* x = (const float*)d_in[0];       // [4,2048,1024]
  const float* wqkv = (const float*)d_in[1];    // [3072,1024]
  const float* wo = (const float*)d_in[2];      // [1024,1024]
  float* out = (float*)d_out;                   // [4,2048,1024] fp32

  ushort* xh = (ushort*)d_ws;                          // 8192*1024
  ushort* wqkvh = xh + (size_t)8192 * 1024;            // 3072*1024
  ushort* woh = wqkvh + (size_t)3072 * 1024;           // 1024*1024
  ushort* qkvh = woh + (size_t)1024 * 1024;            // 8192*3072
  ushort* attnh = qkvh + (size_t)8192 * 3072;          // 8192*1024
  ushort* vtg = attnh + (size_t)8192 * 1024;           // 64*64*2048
  // total ws use: ~109 MB

  cast_f32_f16<<<8192, 256, 0, stream>>>(x, xh);
  cast_f32_f16<<<3072, 256, 0, stream>>>(wqkv, wqkvh);
  cast_f32_f16<<<1024, 256, 0, stream>>>(wo, woh);

  gemm_bt<1><<<dim3(24, 64), 256, 0, stream>>>(xh, wqkvh, qkvh, 8192, 3072, 1024);
  vtrans<<<dim3(32, 64), 256, 0, stream>>>(qkvh, vtg);
  attn_fused<<<dim3(16, 64), 256, 0, stream>>>(qkvh, vtg, attnh);
  gemm_bt<0><<<dim3(8, 64), 256, 0, stream>>>(attnh, woh, out, 8192, 1024, 1024);
}